// Round 8
// baseline (229.551 us; speedup 1.0000x reference)
//
#include <hip/hip_runtime.h>
#include <hip/hip_bf16.h>
#include <cstdint>

#define HH 128
#define LL 4
#define BB 128
#define NNODE 4096
#define EIN 325
#define NBLK 1024            // block = (b, q4): 4 src x 32 dst = 128 edges

// packed-weight fragment offsets (per layer, 1KB frags)
#define OFF_W1  0            // [W1a(4ks);W1b(4ks);W1d(2ks)] : 10 ks x 8 nf = 80
#define OFF_W2  80           // 4 ks x 8 nf = 32
#define OFF_NW1 112          // 8 ks x 8 nf = 64
#define OFF_NW2 176          // 4 ks x 8 nf = 32
#define FR_PER_L 208

typedef __attribute__((ext_vector_type(8))) short short8;
typedef __attribute__((ext_vector_type(4))) float float4v;

#define MFMA __builtin_amdgcn_mfma_f32_16x16x32_bf16

__device__ __forceinline__ float silu_f(float x) {
    return x / (1.0f + __expf(-x));
}

__device__ __forceinline__ uint16_t f2bf(float x) {
    uint32_t u = __builtin_bit_cast(uint32_t, x);
    u += 0x7FFFu + ((u >> 16) & 1u);   // RNE
    return (uint16_t)(u >> 16);
}

__device__ __forceinline__ short8 ldw(const uint4* wpl, int fidx, int lane) {
    return *reinterpret_cast<const short8*>(&wpl[(size_t)fidx*64 + lane]);
}

// ---------- fused prep kernel: roles by blockIdx ----------
// [0,1024): dis pack   [1024,1128): weight pack   [1128,1640): Cc   [1640,2152): h0
__global__ __launch_bounds__(256) void k_prep(
    const int* __restrict__ at, const float* __restrict__ frac,
    const float* __restrict__ lat, const float* __restrict__ emb,
    const float* __restrict__ ew1, const float* __restrict__ eb1,
    const float* __restrict__ ew2, const float* __restrict__ nw1,
    const float* __restrict__ nw2,
    uint4* __restrict__ disP, uint4* __restrict__ wp,
    float* __restrict__ h0, float* __restrict__ Cc)
{
    __shared__ uint16_t sm[8192];    // 16KB; cc role aliases first bytes as float[9]
    int gid = blockIdx.x, t = threadIdx.x;

    if (gid < 1024) {
        // ---- dis: 128 edges -> 16 MFMA A-frags (2 ks x 8 mtiles) ----
        #pragma unroll
        for (int z = 0; z < 4; ++z) ((uint4*)sm)[t + 256*z] = uint4{0,0,0,0};
        __syncthreads();
        int b = gid >> 3, q4 = gid & 7;
        int e2 = t >> 1, half = t & 1;
        int i = q4*4 + (e2 >> 5), j = e2 & 31;
        float dx[3];
        #pragma unroll
        for (int d = 0; d < 3; ++d)
            dx[d] = frac[(b*32 + j)*3 + d] - frac[(b*32 + i)*3 + d];
        int T = e2 >> 4, rr = e2 & 15;
        #pragma unroll
        for (int kk = 0; kk < 30; ++kk) {
            int d = kk / 10, f = kk % 10;
            float ang = 6.28318530717958647692f * (float)f * dx[d];
            float v = half ? __cosf(ang) : __sinf(ang);
            int k = kk + 30*half;
            int ks = k >> 5, g = (k >> 3) & 3, ii = k & 7;
            sm[((ks*8 + T)*64 + g*16 + rr)*8 + ii] = f2bf(v);
        }
        __syncthreads();
        uint4* dst = disP + (size_t)gid * 1024;
        const uint4* smv = (const uint4*)sm;
        #pragma unroll
        for (int z = 0; z < 4; ++z) dst[t + 256*z] = smv[t + 256*z];
    } else if (gid < 1128) {
        // ---- weight pack ----
        int jidx = gid - 1024;
        int lay = jidx / 26, jj = jidx % 26;
        int wv = t >> 6, lane = t & 63, g = lane >> 4, col = lane & 15;
        int ks, base, type;
        if (jj < 10)      { ks = jj;      base = OFF_W1;  type = 0; }
        else if (jj < 14) { ks = jj - 10; base = OFF_W2;  type = 1; }
        else if (jj < 22) { ks = jj - 14; base = OFF_NW1; type = 2; }
        else              { ks = jj - 22; base = OFF_NW2; type = 3; }
        for (int nn = 0; nn < 2; ++nn) {
            int nf = 2*wv + nn;
            int n = nf*16 + col;
            uint16_t vals[8];
            #pragma unroll
            for (int ii = 0; ii < 8; ++ii) {
                int gk = 32*ks + 8*g + ii;
                float v = 0.f;
                if (type == 0) {
                    if (gk < 256)       v = ew1[((size_t)lay*EIN + gk)*HH + n];
                    else if (gk < 316)  v = ew1[((size_t)lay*EIN + gk + 9)*HH + n];
                } else if (type == 1)   v = ew2[((size_t)lay*HH + gk)*HH + n];
                else if (type == 2)     v = nw1[((size_t)lay*2*HH + gk)*HH + n];
                else                    v = nw2[((size_t)lay*HH + gk)*HH + n];
                vals[ii] = f2bf(v);
            }
            wp[((size_t)lay*FR_PER_L + base + ks*8 + nf)*64 + lane] = *(const uint4*)vals;
        }
    } else if (gid < 1640) {
        // ---- Cc = eb1 + lat_ip @ W1c ----
        float* lip = (float*)sm;
        int blk = gid - 1128;
        int lay = blk >> 7, b = blk & 127;
        if (t < 9) {
            int i = t / 3, k2 = t % 3;
            const float* lb = lat + b*9;
            lip[t] = lb[i*3]*lb[k2*3] + lb[i*3+1]*lb[k2*3+1] + lb[i*3+2]*lb[k2*3+2];
        }
        __syncthreads();
        if (t < 128) {
            float acc = eb1[lay*HH + t];
            #pragma unroll
            for (int k = 0; k < 9; ++k)
                acc += lip[k] * ew1[((size_t)lay*EIN + 2*HH + k)*HH + t];
            Cc[(size_t)blk*HH + t] = acc;
        }
    } else {
        // ---- h0 gather (vectorized) ----
        int idx = (gid - 1640)*256 + t;    // < 131072
        int n = idx >> 5, cq = idx & 31;
        float4v v = *(const float4v*)&emb[((size_t)(at[n]-1))*HH + cq*4];
        *(float4v*)&h0[(size_t)n*HH + cq*4] = v;
    }
}

// ---------- fused layer kernel ----------
// block = (b,q4): src nodes b*32+q4*4+{0..3}, all 32 dst. M=128 edges. 4 waves (2x2).
// m1 = Cc + A'[src] (acc init) + dis@W1d (MFMA) + Bv[dst] (fp32 LDS adds).
// LDS exactly 40960B -> 4 blocks/CU. aggB/u1B overlay dead hHi rows.
__global__ __launch_bounds__(256, 4) void k_layer(
    const float* __restrict__ h_in, float* __restrict__ h_out,
    const uint4* __restrict__ disP, const uint4* __restrict__ wpl,
    const float* __restrict__ Cc_l, const float* __restrict__ b2,
    const float* __restrict__ nb1, const float* __restrict__ nb2)
{
    __shared__ uint4 smem4[2560];                // 40960 B
    char* smem = (char*)smem4;
    char* hHi = smem;                            // [32] rows x 256B bf16, XOR-swizzled
    float* Af = (float*)(smem + 8192);           // [4][132] f32 A' = h_src @ W1a
    float* Bf = (float*)(smem + 10304);          // [32][132] f32 Bv = h @ W1b (ends 27200)
    char* sS  = smem + 8192;                     // overlays Af/Bf after GEMM1: [128]x256B swizzled

    int bid = blockIdx.x;
    int b = bid >> 3, q4 = bid & 7;
    // aggB/u1B overlay hHi rows of OTHER q4 groups (dead after P1; own rows stay live)
    uint16_t* aggB = (uint16_t*)(smem + ((((q4 + 1) & 7)) << 10));   // [4][128] bf16, 1KB
    uint16_t* u1B  = (uint16_t*)(smem + ((((q4 + 2) & 7)) << 10));   // [4][128] bf16, 1KB
    int t = threadIdx.x;
    int w = t >> 6, l = t & 63;
    int wm = w >> 1, wn = w & 1;
    int g = l >> 4, rr = l & 15;

    // prefetch dis A-frags (global, long latency -> cover under P0/P1)
    short8 dfr[2][4];
    #pragma unroll
    for (int ks = 0; ks < 2; ++ks)
        #pragma unroll
        for (int mf = 0; mf < 4; ++mf)
            dfr[ks][mf] = *(const short8*)&disP[((size_t)(bid*2 + ks)*8 + 4*wm + mf)*64 + l];

    // ---- P0: stage h tile (32 rows) bf16, swizzled ----
    {
        int row = t >> 3, czb = (t & 7) * 16;
        const float* hp = h_in + (size_t)(b*32 + row)*HH + czb;
        uint16_t ph[16];
        #pragma unroll
        for (int z = 0; z < 16; z += 4) {
            float4v v = *(const float4v*)(hp + z);
            #pragma unroll
            for (int y = 0; y < 4; ++y) ph[z+y] = f2bf(v[y]);
        }
        int sw = (row & 7) << 4;
        int base = row * 256;
        *(uint4*)(hHi + base + ((2*czb) ^ sw))      = *(const uint4*)&ph[0];
        *(uint4*)(hHi + base + ((2*czb + 16) ^ sw)) = *(const uint4*)&ph[8];
    }
    __syncthreads();

    // ---- P1: A' = h_src@W1a (mt0, rows replicated), Bv = h@W1b (mt1,2); wave owns 2 nf cols ----
    {
        float4v pacc[3][2];
        #pragma unroll
        for (int mt = 0; mt < 3; ++mt)
            #pragma unroll
            for (int nfl = 0; nfl < 2; ++nfl) pacc[mt][nfl] = (float4v){0.f,0.f,0.f,0.f};
        #pragma unroll
        for (int ks = 0; ks < 4; ++ks) {
            short8 wa[2], wb[2];
            #pragma unroll
            for (int nfl = 0; nfl < 2; ++nfl) {
                wa[nfl] = ldw(wpl, OFF_W1      + ks*8 + 2*w + nfl, l);
                wb[nfl] = ldw(wpl, OFF_W1 + 32 + ks*8 + 2*w + nfl, l);
            }
            #pragma unroll
            for (int mt = 0; mt < 3; ++mt) {
                int R = (mt == 0) ? (q4*4 + (rr & 3)) : ((mt - 1)*16 + rr);
                short8 a = *(const short8*)(hHi + R*256 + ((64*ks + 16*g) ^ ((R & 7) << 4)));
                #pragma unroll
                for (int nfl = 0; nfl < 2; ++nfl)
                    pacc[mt][nfl] = MFMA(a, (mt == 0) ? wa[nfl] : wb[nfl], pacc[mt][nfl], 0, 0, 0);
            }
        }
        // write Af (rows 0..3, g==0 lanes) and Bf (rows 0..31), fp32, stride 132
        #pragma unroll
        for (int nfl = 0; nfl < 2; ++nfl) {
            int n = 32*w + 16*nfl + rr;
            if (g == 0) {
                #pragma unroll
                for (int r = 0; r < 4; ++r) Af[r*132 + n] = pacc[0][nfl][r];
            }
            #pragma unroll
            for (int r = 0; r < 4; ++r) Bf[(4*g + r)*132 + n]      = pacc[1][nfl][r];
            #pragma unroll
            for (int r = 0; r < 4; ++r) Bf[(16 + 4*g + r)*132 + n] = pacc[2][nfl][r];
        }
    }
    __syncthreads();

    float ccv[4], b2v[4];
    #pragma unroll
    for (int nf = 0; nf < 4; ++nf) {
        ccv[nf] = Cc_l[b*HH + 64*wn + 16*nf + rr];
        b2v[nf] = b2[64*wn + 16*nf + rr];
    }

    // ---- GEMM1: acc = (Cc + A'[src]) + dis@W1d, then += Bv[dst] ----
    float4v acc[4][4];
    #pragma unroll
    for (int mf = 0; mf < 4; ++mf) {
        int srcr = 2*wm + (mf >> 1);     // = T>>1, T = 4*wm+mf
        #pragma unroll
        for (int nf = 0; nf < 4; ++nf) {
            float iv = ccv[nf] + Af[srcr*132 + 64*wn + 16*nf + rr];
            acc[mf][nf] = (float4v){iv, iv, iv, iv};
        }
    }
    #pragma unroll
    for (int ks = 0; ks < 2; ++ks) {
        short8 wf[4];
        #pragma unroll
        for (int nf = 0; nf < 4; ++nf)
            wf[nf] = ldw(wpl, OFF_W1 + 64 + ks*8 + 4*wn + nf, l);
        #pragma unroll
        for (int mf = 0; mf < 4; ++mf)
            #pragma unroll
            for (int nf = 0; nf < 4; ++nf)
                acc[mf][nf] = MFMA(dfr[ks][mf], wf[nf], acc[mf][nf], 0, 0, 0);
    }
    // += Bv[dst]: direct LDS reads (2 uses each -> re-read; 2-way aliasing is free)
    #pragma unroll
    for (int mf = 0; mf < 4; ++mf)
        #pragma unroll
        for (int r = 0; r < 4; ++r) {
            const float* bp = &Bf[(16*(mf & 1) + 4*g + r)*132 + 64*wn + rr];
            #pragma unroll
            for (int nf = 0; nf < 4; ++nf)
                acc[mf][nf][r] += bp[16*nf];
        }
    __syncthreads();   // all Af/Bf reads done before sS overlay writes

    // ---- silu -> sS (swizzled bf16) ----
    #pragma unroll
    for (int mf = 0; mf < 4; ++mf) {
        int T = 4*wm + mf;
        #pragma unroll
        for (int nf = 0; nf < 4; ++nf) {
            int n = 64*wn + 16*nf + rr;
            #pragma unroll
            for (int r = 0; r < 4; ++r) {
                int m = 16*T + 4*g + r;
                *(uint16_t*)(sS + m*256 + ((2*n) ^ ((m & 7) << 4))) = f2bf(silu_f(acc[mf][nf][r]));
            }
        }
    }
    __syncthreads();

    // ---- GEMM2: s(128x128) @ W2 ----
    #pragma unroll
    for (int mf = 0; mf < 4; ++mf)
        #pragma unroll
        for (int nf = 0; nf < 4; ++nf)
            acc[mf][nf] = (float4v){0.f, 0.f, 0.f, 0.f};
    #pragma unroll
    for (int ks = 0; ks < 4; ++ks) {
        short8 wf[4];
        #pragma unroll
        for (int nf = 0; nf < 4; ++nf)
            wf[nf] = ldw(wpl, OFF_W2 + ks*8 + 4*wn + nf, l);
        #pragma unroll
        for (int mf = 0; mf < 4; ++mf) {
            int m = 16*(4*wm + mf) + rr;
            short8 a = *(const short8*)(sS + m*256 + ((64*ks + 16*g) ^ ((m & 7) << 4)));
            #pragma unroll
            for (int nf = 0; nf < 4; ++nf)
                acc[mf][nf] = MFMA(a, wf[nf], acc[mf][nf], 0, 0, 0);
        }
    }

    // ---- +b2, silu, mean over 32 j -> aggB bf16 (aggB is in hHi region, no sS race) ----
    #pragma unroll
    for (int u = 0; u < 2; ++u) {            // i_loc = 2*wm + u
        #pragma unroll
        for (int nf = 0; nf < 4; ++nf) {
            float v = 0.f;
            #pragma unroll
            for (int mm = 0; mm < 2; ++mm)
                #pragma unroll
                for (int r = 0; r < 4; ++r)
                    v += silu_f(acc[2*u + mm][nf][r] + b2v[nf]);
            v += __shfl_xor(v, 16);
            v += __shfl_xor(v, 32);
            if (g == 0)
                aggB[(2*wm + u)*128 + 64*wn + 16*nf + rr] = f2bf(v * (1.0f/32.0f));
        }
    }
    __syncthreads();

    // ---- node MLP1: [h | agg] @ NW1 ----
    float4v uacc[2];
    #pragma unroll
    for (int nfl = 0; nfl < 2; ++nfl) uacc[nfl] = (float4v){0.f, 0.f, 0.f, 0.f};
    #pragma unroll
    for (int ks = 0; ks < 8; ++ks) {
        short8 a;
        if (ks < 4) {
            int R = q4*4 + (rr & 3);
            a = *(const short8*)(hHi + R*256 + ((64*ks + 16*g) ^ ((R & 7) << 4)));
        } else {
            a = *(const short8*)&aggB[(rr & 3)*128 + 32*(ks - 4) + 8*g];
        }
        #pragma unroll
        for (int nfl = 0; nfl < 2; ++nfl)
            uacc[nfl] = MFMA(a, ldw(wpl, OFF_NW1 + ks*8 + 2*w + nfl, l), uacc[nfl], 0, 0, 0);
    }
    if (g == 0) {
        #pragma unroll
        for (int nfl = 0; nfl < 2; ++nfl)
            #pragma unroll
            for (int r = 0; r < 4; ++r) {
                int col = (2*w + nfl)*16 + rr;
                u1B[r*128 + col] = f2bf(silu_f(uacc[nfl][r] + nb1[col]));
            }
    }
    __syncthreads();

    // ---- node MLP2 + residual ----
    float4v vacc[2];
    #pragma unroll
    for (int nfl = 0; nfl < 2; ++nfl) vacc[nfl] = (float4v){0.f, 0.f, 0.f, 0.f};
    #pragma unroll
    for (int ks = 0; ks < 4; ++ks) {
        short8 a = *(const short8*)&u1B[(rr & 3)*128 + 32*ks + 8*g];
        #pragma unroll
        for (int nfl = 0; nfl < 2; ++nfl)
            vacc[nfl] = MFMA(a, ldw(wpl, OFF_NW2 + ks*8 + 2*w + nfl, l), vacc[nfl], 0, 0, 0);
    }
    if (g == 0) {
        #pragma unroll
        for (int nfl = 0; nfl < 2; ++nfl)
            #pragma unroll
            for (int r = 0; r < 4; ++r) {
                int col = (2*w + nfl)*16 + rr;
                size_t node = (size_t)(b*32 + q4*4 + r);
                h_out[node*HH + col] = h_in[node*HH + col] + silu_f(vacc[nfl][r] + nb2[col]);
            }
    }
}

// graph mean-pool + out projection
__global__ __launch_bounds__(128) void k_pool(const float* __restrict__ h, const float* __restrict__ ow,
                       float* __restrict__ out) {
    __shared__ float sm_g[HH];
    int b = blockIdx.x, c = threadIdx.x;
    float s = 0.f;
    for (int n = 0; n < 32; ++n) s += h[(size_t)(b*32 + n)*HH + c];
    sm_g[c] = s * (1.0f/32.0f);
    __syncthreads();
    float acc = 0.f;
    for (int k = 0; k < HH; ++k) acc += sm_g[k] * ow[k*HH + c];
    out[(size_t)b*HH + c] = acc;
}

extern "C" void kernel_launch(void* const* d_in, const int* in_sizes, int n_in,
                              void* d_out, int out_size, void* d_ws, size_t ws_size,
                              hipStream_t stream) {
    const int*   atom_types = (const int*)d_in[0];
    const float* frac       = (const float*)d_in[1];
    const float* lat        = (const float*)d_in[2];
    const float* node_emb   = (const float*)d_in[5];
    const float* ew1        = (const float*)d_in[6];
    const float* eb1        = (const float*)d_in[7];
    const float* ew2        = (const float*)d_in[8];
    const float* eb2        = (const float*)d_in[9];
    const float* nw1        = (const float*)d_in[10];
    const float* nb1        = (const float*)d_in[11];
    const float* nw2        = (const float*)d_in[12];
    const float* nb2        = (const float*)d_in[13];
    const float* ow         = (const float*)d_in[14];
    float* out = (float*)d_out;

    char* ws = (char*)d_ws;
    uint4* disP = (uint4*)ws; ws += (size_t)NBLK*1024*16;          // 16 MB
    uint4* wp   = (uint4*)ws; ws += (size_t)LL*FR_PER_L*64*16;     // 832 KB
    float* hA   = (float*)ws; ws += (size_t)NNODE*HH*4;            // 2 MB
    float* hB   = (float*)ws; ws += (size_t)NNODE*HH*4;            // 2 MB
    float* Cc   = (float*)ws; ws += (size_t)LL*BB*HH*4;            // 256 KB

    k_prep<<<2152, 256, 0, stream>>>(atom_types, frac, lat, node_emb,
                                     ew1, eb1, ew2, nw1, nw2,
                                     disP, wp, hA, Cc);

    float* hin = hA; float* hout = hB;
    for (int l = 0; l < LL; ++l) {
        k_layer<<<NBLK, 256, 0, stream>>>(hin, hout, disP, wp + (size_t)l*FR_PER_L*64,
                                          Cc + (size_t)l*BB*HH, eb2 + (size_t)l*HH,
                                          nb1 + (size_t)l*HH, nb2 + (size_t)l*HH);
        float* tmp = hin; hin = hout; hout = tmp;
    }
    k_pool<<<BB, HH, 0, stream>>>(hin, ow, out);
}

// Round 9
// 192.250 us; speedup vs baseline: 1.1940x; 1.1940x over previous
//
#include <hip/hip_runtime.h>
#include <hip/hip_bf16.h>
#include <cstdint>

#define HH 128
#define LL 4
#define BB 128
#define NNODE 4096
#define EIN 325
#define NBLK 1024            // block = (b, q4): 4 src x 32 dst = 128 edges

// packed-weight fragment offsets (per layer, 1KB frags)
#define OFF_W1  0            // [W1a(4ks);W1b(4ks);W1d(2ks)] : 10 ks x 8 nf = 80
#define OFF_W2  80           // 4 ks x 8 nf = 32
#define OFF_NW1 112          // 8 ks x 8 nf = 64
#define OFF_NW2 176          // 4 ks x 8 nf = 32
#define FR_PER_L 208

typedef __attribute__((ext_vector_type(8))) short short8;
typedef __attribute__((ext_vector_type(4))) float float4v;

#define MFMA __builtin_amdgcn_mfma_f32_16x16x32_bf16

// 2xf32 -> packed bf16 (RNE), src0 -> low half [gfx950 v_cvt_pk_bf16_f32]
__device__ __forceinline__ uint32_t cvtpk2(float lo, float hi) {
    uint32_t r;
    asm("v_cvt_pk_bf16_f32 %0, %1, %2" : "=v"(r) : "v"(lo), "v"(hi));
    return r;
}
__device__ __forceinline__ uint16_t f2bf(float x) { return (uint16_t)cvtpk2(x, x); }

// silu via raw exp2/rcp (5 instr, 2 trans; ~1ulp rcp error ok for bf16 pipeline)
__device__ __forceinline__ float silu_f(float x) {
    float e;
    asm("v_exp_f32 %0, %1" : "=v"(e) : "v"(-1.44269504088896341f * x));
    float r;
    asm("v_rcp_f32 %0, %1" : "=v"(r) : "v"(1.0f + e));
    return x * r;
}

__device__ __forceinline__ short8 ldw(const uint4* wpl, int fidx, int lane) {
    return *reinterpret_cast<const short8*>(&wpl[(size_t)fidx*64 + lane]);
}

// ---------- fused prep kernel: roles by blockIdx ----------
// [0,1024): dis pack   [1024,1128): weight pack   [1128,1640): Cc   [1640,2152): h0
__global__ __launch_bounds__(256) void k_prep(
    const int* __restrict__ at, const float* __restrict__ frac,
    const float* __restrict__ lat, const float* __restrict__ emb,
    const float* __restrict__ ew1, const float* __restrict__ eb1,
    const float* __restrict__ ew2, const float* __restrict__ nw1,
    const float* __restrict__ nw2,
    uint4* __restrict__ disP, uint4* __restrict__ wp,
    float* __restrict__ h0, float* __restrict__ Cc)
{
    __shared__ uint16_t sm[8192];    // 16KB; cc role aliases first bytes as float[9]
    int gid = blockIdx.x, t = threadIdx.x;

    if (gid < 1024) {
        // ---- dis: 128 edges -> 16 MFMA A-frags (2 ks x 8 mtiles) ----
        #pragma unroll
        for (int z = 0; z < 4; ++z) ((uint4*)sm)[t + 256*z] = uint4{0,0,0,0};
        __syncthreads();
        int b = gid >> 3, q4 = gid & 7;
        int e2 = t >> 1, half = t & 1;
        int i = q4*4 + (e2 >> 5), j = e2 & 31;
        float dx[3];
        #pragma unroll
        for (int d = 0; d < 3; ++d)
            dx[d] = frac[(b*32 + j)*3 + d] - frac[(b*32 + i)*3 + d];
        int T = e2 >> 4, rr = e2 & 15;
        #pragma unroll
        for (int kk = 0; kk < 30; ++kk) {
            int d = kk / 10, f = kk % 10;
            float ang = 6.28318530717958647692f * (float)f * dx[d];
            float v = half ? __cosf(ang) : __sinf(ang);
            int k = kk + 30*half;
            int ks = k >> 5, g = (k >> 3) & 3, ii = k & 7;
            sm[((ks*8 + T)*64 + g*16 + rr)*8 + ii] = f2bf(v);
        }
        __syncthreads();
        uint4* dst = disP + (size_t)gid * 1024;
        const uint4* smv = (const uint4*)sm;
        #pragma unroll
        for (int z = 0; z < 4; ++z) dst[t + 256*z] = smv[t + 256*z];
    } else if (gid < 1128) {
        // ---- weight pack ----
        int jidx = gid - 1024;
        int lay = jidx / 26, jj = jidx % 26;
        int wv = t >> 6, lane = t & 63, g = lane >> 4, col = lane & 15;
        int ks, base, type;
        if (jj < 10)      { ks = jj;      base = OFF_W1;  type = 0; }
        else if (jj < 14) { ks = jj - 10; base = OFF_W2;  type = 1; }
        else if (jj < 22) { ks = jj - 14; base = OFF_NW1; type = 2; }
        else              { ks = jj - 22; base = OFF_NW2; type = 3; }
        for (int nn = 0; nn < 2; ++nn) {
            int nf = 2*wv + nn;
            int n = nf*16 + col;
            uint16_t vals[8];
            #pragma unroll
            for (int ii = 0; ii < 8; ++ii) {
                int gk = 32*ks + 8*g + ii;
                float v = 0.f;
                if (type == 0) {
                    if (gk < 256)       v = ew1[((size_t)lay*EIN + gk)*HH + n];
                    else if (gk < 316)  v = ew1[((size_t)lay*EIN + gk + 9)*HH + n];
                } else if (type == 1)   v = ew2[((size_t)lay*HH + gk)*HH + n];
                else if (type == 2)     v = nw1[((size_t)lay*2*HH + gk)*HH + n];
                else                    v = nw2[((size_t)lay*HH + gk)*HH + n];
                vals[ii] = f2bf(v);
            }
            wp[((size_t)lay*FR_PER_L + base + ks*8 + nf)*64 + lane] = *(const uint4*)vals;
        }
    } else if (gid < 1640) {
        // ---- Cc = eb1 + lat_ip @ W1c ----
        float* lip = (float*)sm;
        int blk = gid - 1128;
        int lay = blk >> 7, b = blk & 127;
        if (t < 9) {
            int i = t / 3, k2 = t % 3;
            const float* lb = lat + b*9;
            lip[t] = lb[i*3]*lb[k2*3] + lb[i*3+1]*lb[k2*3+1] + lb[i*3+2]*lb[k2*3+2];
        }
        __syncthreads();
        if (t < 128) {
            float acc = eb1[lay*HH + t];
            #pragma unroll
            for (int k = 0; k < 9; ++k)
                acc += lip[k] * ew1[((size_t)lay*EIN + 2*HH + k)*HH + t];
            Cc[(size_t)blk*HH + t] = acc;
        }
    } else {
        // ---- h0 gather (vectorized) ----
        int idx = (gid - 1640)*256 + t;    // < 131072
        int n = idx >> 5, cq = idx & 31;
        float4v v = *(const float4v*)&emb[((size_t)(at[n]-1))*HH + cq*4];
        *(float4v*)&h0[(size_t)n*HH + cq*4] = v;
    }
}

// ---------- fused layer kernel (512 threads = 8 waves, 2M x 4N) ----------
// block = (b,q4): src nodes b*32+q4*4+{0..3}, all 32 dst. M=128 edges.
// m1 = Cc + A'[src] (acc init) + dis@W1d (MFMA) + Bv[dst] (fp32 LDS adds).
__global__ __launch_bounds__(512, 4) void k_layer(
    const float* __restrict__ h_in, float* __restrict__ h_out,
    const uint4* __restrict__ disP, const uint4* __restrict__ wpl,
    const float* __restrict__ Cc_l, const float* __restrict__ b2,
    const float* __restrict__ nb1, const float* __restrict__ nb2)
{
    __shared__ uint4 smem4[2560];                // 40960 B
    char* smem = (char*)smem4;
    char* hHi = smem;                            // [32] rows x 256B bf16, XOR-swizzled
    float* Af = (float*)(smem + 8192);           // [4][132] f32 A' = h_src @ W1a
    float* Bf = (float*)(smem + 10304);          // [32][132] f32 Bv = h @ W1b (ends 27200)
    char* sS  = smem + 8192;                     // overlays Af/Bf after GEMM1: [128]x256B swizzled

    int bid = blockIdx.x;
    int b = bid >> 3, q4 = bid & 7;
    // aggB/u1B overlay hHi rows of OTHER q4 groups (dead after P1; own rows stay live)
    uint16_t* aggB = (uint16_t*)(smem + ((((q4 + 1) & 7)) << 10));   // [4][128] bf16, 1KB
    uint16_t* u1B  = (uint16_t*)(smem + ((((q4 + 2) & 7)) << 10));   // [4][128] bf16, 1KB
    int t = threadIdx.x;
    int w = t >> 6, l = t & 63;
    int wm = w >> 2, wn = w & 3;                 // 2 x 4 wave grid
    int g = l >> 4, rr = l & 15;

    // prefetch dis A-frags (global, long latency -> cover under P0/P1)
    short8 dfr[2][4];
    #pragma unroll
    for (int ks = 0; ks < 2; ++ks)
        #pragma unroll
        for (int mf = 0; mf < 4; ++mf)
            dfr[ks][mf] = *(const short8*)&disP[((size_t)(bid*2 + ks)*8 + 4*wm + mf)*64 + l];

    // ---- P0: stage h tile (32 rows) bf16, swizzled (cvt_pk packed) ----
    {
        int row = t >> 4, cz = (t & 15) * 8;
        const float* hp = h_in + (size_t)(b*32 + row)*HH + cz;
        float4v v0 = *(const float4v*)hp;
        float4v v1 = *(const float4v*)(hp + 4);
        uint32_t pw[4];
        pw[0] = cvtpk2(v0[0], v0[1]); pw[1] = cvtpk2(v0[2], v0[3]);
        pw[2] = cvtpk2(v1[0], v1[1]); pw[3] = cvtpk2(v1[2], v1[3]);
        *(uint4*)(hHi + row*256 + ((2*cz) ^ ((row & 7) << 4))) = *(const uint4*)pw;
    }
    __syncthreads();

    // ---- P1: A' = h_src@W1a (mt0, rows replicated), Bv = h@W1b (mt1,2); wave owns nf8=w ----
    {
        float4v pacc[3];
        #pragma unroll
        for (int mt = 0; mt < 3; ++mt) pacc[mt] = (float4v){0.f,0.f,0.f,0.f};
        #pragma unroll
        for (int ks = 0; ks < 4; ++ks) {
            short8 wa = ldw(wpl, OFF_W1      + ks*8 + w, l);
            short8 wb = ldw(wpl, OFF_W1 + 32 + ks*8 + w, l);
            #pragma unroll
            for (int mt = 0; mt < 3; ++mt) {
                int R = (mt == 0) ? (q4*4 + (rr & 3)) : ((mt - 1)*16 + rr);
                short8 a = *(const short8*)(hHi + R*256 + ((64*ks + 16*g) ^ ((R & 7) << 4)));
                pacc[mt] = MFMA(a, (mt == 0) ? wa : wb, pacc[mt], 0, 0, 0);
            }
        }
        int n = 16*w + rr;
        if (g == 0) {
            #pragma unroll
            for (int r = 0; r < 4; ++r) Af[r*132 + n] = pacc[0][r];
        }
        #pragma unroll
        for (int r = 0; r < 4; ++r) Bf[(4*g + r)*132 + n]      = pacc[1][r];
        #pragma unroll
        for (int r = 0; r < 4; ++r) Bf[(16 + 4*g + r)*132 + n] = pacc[2][r];
    }
    __syncthreads();

    float ccv[2], b2v[2];
    #pragma unroll
    for (int nf = 0; nf < 2; ++nf) {
        ccv[nf] = Cc_l[b*HH + 32*wn + 16*nf + rr];
        b2v[nf] = b2[32*wn + 16*nf + rr];
    }

    // ---- GEMM1: acc = (Cc + A'[src]) + dis@W1d, then += Bv[dst] ----
    float4v acc[4][2];
    #pragma unroll
    for (int mf = 0; mf < 4; ++mf) {
        int srcr = 2*wm + (mf >> 1);     // = T>>1, T = 4*wm+mf
        #pragma unroll
        for (int nf = 0; nf < 2; ++nf) {
            float iv = ccv[nf] + Af[srcr*132 + 32*wn + 16*nf + rr];
            acc[mf][nf] = (float4v){iv, iv, iv, iv};
        }
    }
    #pragma unroll
    for (int ks = 0; ks < 2; ++ks) {
        short8 wf[2];
        #pragma unroll
        for (int nf = 0; nf < 2; ++nf)
            wf[nf] = ldw(wpl, OFF_W1 + 64 + ks*8 + 2*wn + nf, l);
        #pragma unroll
        for (int mf = 0; mf < 4; ++mf)
            #pragma unroll
            for (int nf = 0; nf < 2; ++nf)
                acc[mf][nf] = MFMA(dfr[ks][mf], wf[nf], acc[mf][nf], 0, 0, 0);
    }
    // += Bv[dst]: direct LDS reads (2-way aliasing free)
    #pragma unroll
    for (int mf = 0; mf < 4; ++mf)
        #pragma unroll
        for (int r = 0; r < 4; ++r) {
            const float* bp = &Bf[(16*(mf & 1) + 4*g + r)*132 + 32*wn + rr];
            #pragma unroll
            for (int nf = 0; nf < 2; ++nf)
                acc[mf][nf][r] += bp[16*nf];
        }
    __syncthreads();   // all Af/Bf reads done before sS overlay writes

    // ---- silu -> sS (swizzled bf16) ----
    #pragma unroll
    for (int mf = 0; mf < 4; ++mf) {
        int T = 4*wm + mf;
        #pragma unroll
        for (int nf = 0; nf < 2; ++nf) {
            int n = 32*wn + 16*nf + rr;
            #pragma unroll
            for (int r = 0; r < 4; ++r) {
                int m = 16*T + 4*g + r;
                *(uint16_t*)(sS + m*256 + ((2*n) ^ ((m & 7) << 4))) = f2bf(silu_f(acc[mf][nf][r]));
            }
        }
    }
    __syncthreads();

    // ---- GEMM2: s(128x128) @ W2 ----
    #pragma unroll
    for (int mf = 0; mf < 4; ++mf)
        #pragma unroll
        for (int nf = 0; nf < 2; ++nf)
            acc[mf][nf] = (float4v){0.f, 0.f, 0.f, 0.f};
    #pragma unroll
    for (int ks = 0; ks < 4; ++ks) {
        short8 wf[2];
        #pragma unroll
        for (int nf = 0; nf < 2; ++nf)
            wf[nf] = ldw(wpl, OFF_W2 + ks*8 + 2*wn + nf, l);
        #pragma unroll
        for (int mf = 0; mf < 4; ++mf) {
            int m = 16*(4*wm + mf) + rr;
            short8 a = *(const short8*)(sS + m*256 + ((64*ks + 16*g) ^ ((m & 7) << 4)));
            #pragma unroll
            for (int nf = 0; nf < 2; ++nf)
                acc[mf][nf] = MFMA(a, wf[nf], acc[mf][nf], 0, 0, 0);
        }
    }

    // ---- +b2, silu, mean over 32 j -> aggB bf16 (aggB is in hHi region, no sS race) ----
    #pragma unroll
    for (int u = 0; u < 2; ++u) {            // i_loc = 2*wm + u
        #pragma unroll
        for (int nf = 0; nf < 2; ++nf) {
            float v = 0.f;
            #pragma unroll
            for (int mm = 0; mm < 2; ++mm)
                #pragma unroll
                for (int r = 0; r < 4; ++r)
                    v += silu_f(acc[2*u + mm][nf][r] + b2v[nf]);
            v += __shfl_xor(v, 16);
            v += __shfl_xor(v, 32);
            if (g == 0)
                aggB[(2*wm + u)*128 + 32*wn + 16*nf + rr] = f2bf(v * (1.0f/32.0f));
        }
    }
    __syncthreads();

    // ---- node MLP1: [h | agg] @ NW1 (wave owns nf8 = w) ----
    float4v uacc = (float4v){0.f, 0.f, 0.f, 0.f};
    #pragma unroll
    for (int ks = 0; ks < 8; ++ks) {
        short8 a;
        if (ks < 4) {
            int R = q4*4 + (rr & 3);
            a = *(const short8*)(hHi + R*256 + ((64*ks + 16*g) ^ ((R & 7) << 4)));
        } else {
            a = *(const short8*)&aggB[(rr & 3)*128 + 32*(ks - 4) + 8*g];
        }
        uacc = MFMA(a, ldw(wpl, OFF_NW1 + ks*8 + w, l), uacc, 0, 0, 0);
    }
    if (g == 0) {
        #pragma unroll
        for (int r = 0; r < 4; ++r) {
            int col = 16*w + rr;
            u1B[r*128 + col] = f2bf(silu_f(uacc[r] + nb1[col]));
        }
    }
    __syncthreads();

    // ---- node MLP2 + residual ----
    float4v vacc = (float4v){0.f, 0.f, 0.f, 0.f};
    #pragma unroll
    for (int ks = 0; ks < 4; ++ks) {
        short8 a = *(const short8*)&u1B[(rr & 3)*128 + 32*ks + 8*g];
        vacc = MFMA(a, ldw(wpl, OFF_NW2 + ks*8 + w, l), vacc, 0, 0, 0);
    }
    if (g == 0) {
        #pragma unroll
        for (int r = 0; r < 4; ++r) {
            int col = 16*w + rr;
            size_t node = (size_t)(b*32 + q4*4 + r);
            h_out[node*HH + col] = h_in[node*HH + col] + silu_f(vacc[r] + nb2[col]);
        }
    }
}

// graph mean-pool + out projection
__global__ __launch_bounds__(128) void k_pool(const float* __restrict__ h, const float* __restrict__ ow,
                       float* __restrict__ out) {
    __shared__ float sm_g[HH];
    int b = blockIdx.x, c = threadIdx.x;
    float s = 0.f;
    for (int n = 0; n < 32; ++n) s += h[(size_t)(b*32 + n)*HH + c];
    sm_g[c] = s * (1.0f/32.0f);
    __syncthreads();
    float acc = 0.f;
    for (int k = 0; k < HH; ++k) acc += sm_g[k] * ow[k*HH + c];
    out[(size_t)b*HH + c] = acc;
}

extern "C" void kernel_launch(void* const* d_in, const int* in_sizes, int n_in,
                              void* d_out, int out_size, void* d_ws, size_t ws_size,
                              hipStream_t stream) {
    const int*   atom_types = (const int*)d_in[0];
    const float* frac       = (const float*)d_in[1];
    const float* lat        = (const float*)d_in[2];
    const float* node_emb   = (const float*)d_in[5];
    const float* ew1        = (const float*)d_in[6];
    const float* eb1        = (const float*)d_in[7];
    const float* ew2        = (const float*)d_in[8];
    const float* eb2        = (const float*)d_in[9];
    const float* nw1        = (const float*)d_in[10];
    const float* nb1        = (const float*)d_in[11];
    const float* nw2        = (const float*)d_in[12];
    const float* nb2        = (const float*)d_in[13];
    const float* ow         = (const float*)d_in[14];
    float* out = (float*)d_out;

    char* ws = (char*)d_ws;
    uint4* disP = (uint4*)ws; ws += (size_t)NBLK*1024*16;          // 16 MB
    uint4* wp   = (uint4*)ws; ws += (size_t)LL*FR_PER_L*64*16;     // 832 KB
    float* hA   = (float*)ws; ws += (size_t)NNODE*HH*4;            // 2 MB
    float* hB   = (float*)ws; ws += (size_t)NNODE*HH*4;            // 2 MB
    float* Cc   = (float*)ws; ws += (size_t)LL*BB*HH*4;            // 256 KB

    k_prep<<<2152, 256, 0, stream>>>(atom_types, frac, lat, node_emb,
                                     ew1, eb1, ew2, nw1, nw2,
                                     disP, wp, hA, Cc);

    float* hin = hA; float* hout = hB;
    for (int l = 0; l < LL; ++l) {
        k_layer<<<NBLK, 512, 0, stream>>>(hin, hout, disP, wp + (size_t)l*FR_PER_L*64,
                                          Cc + (size_t)l*BB*HH, eb2 + (size_t)l*HH,
                                          nb1 + (size_t)l*HH, nb2 + (size_t)l*HH);
        float* tmp = hin; hin = hout; hout = tmp;
    }
    k_pool<<<BB, HH, 0, stream>>>(hin, ow, out);
}